// Round 11
// baseline (34.950 us; speedup 1.0000x reference)
//
#include <hip/hip_runtime.h>
#include <stdint.h>

#define D_DIM 768
#define KNEG 100
#define INV_KAPPA 10.0f
#define RDP 128           // dwords per padded i4 row (32 lanes x 4 dwords; 4th = pad)

// ---------------- threefry2x32 (exact JAX semantics) ----------------
__device__ __forceinline__ uint32_t rotl32(uint32_t x, int r) {
  return (x << r) | (x >> (32 - r));
}

#define TF_R4(a, b, c, d)                        \
  x0 += x1; x1 = rotl32(x1, a); x1 ^= x0;        \
  x0 += x1; x1 = rotl32(x1, b); x1 ^= x0;        \
  x0 += x1; x1 = rotl32(x1, c); x1 ^= x0;        \
  x0 += x1; x1 = rotl32(x1, d); x1 ^= x0;

__device__ __forceinline__ void threefry2x32(uint32_t ks0, uint32_t ks1,
                                             uint32_t x0, uint32_t x1,
                                             uint32_t& o0, uint32_t& o1) {
  uint32_t ks2 = ks0 ^ ks1 ^ 0x1BD11BDAu;
  x0 += ks0; x1 += ks1;
  TF_R4(13, 15, 26, 6)   x0 += ks1; x1 += ks2 + 1u;
  TF_R4(17, 29, 16, 24)  x0 += ks2; x1 += ks0 + 2u;
  TF_R4(13, 15, 26, 6)   x0 += ks0; x1 += ks1 + 3u;
  TF_R4(17, 29, 16, 24)  x0 += ks1; x1 += ks2 + 4u;
  TF_R4(13, 15, 26, 6)   x0 += ks2; x1 += ks0 + 5u;
  o0 = x0; o1 = x1;
}

__device__ __forceinline__ int sample_negative(int row, int k, int N) {
  // replicate jax.random.randint(key(42), (N,100), 0, N-1) element (row,k)
  uint32_t a0, b0, a1, b1;
  threefry2x32(0u, 42u, 0u, 2u, a0, b0);   // constant-folds at -O3
  threefry2x32(0u, 42u, 1u, 3u, a1, b1);
  uint32_t total = (uint32_t)N * KNEG;
  uint32_t half = total >> 1;
  uint32_t j = (uint32_t)row * KNEG + (uint32_t)k;
  uint32_t x0 = (j < half) ? j : (j - half);
  uint32_t x1 = (j < half) ? (j + half) : j;
  uint32_t h0, h1, l0, l1;
  threefry2x32(a0, a1, x0, x1, h0, h1);
  threefry2x32(b0, b1, x0, x1, l0, l1);
  uint32_t hb = (j < half) ? h0 : h1;
  uint32_t lb = (j < half) ? l0 : l1;
  uint32_t span = (uint32_t)(N - 1);
  uint32_t mult = 65536u % span;
  mult = (mult * mult) % span;
  uint32_t off = ((hb % span) * mult + (lb % span)) % span;
  int idx = (int)off;
  if (idx >= row) idx++;  // skip self
  return idx;
}

// ---------------- i4 pack + hw dot8 (inline asm: assembles or build fails) ----------------
__device__ __forceinline__ uint32_t pack8_i4(float4 a, float4 b, float f) {
  uint32_t d = 0;
  d |= ((uint32_t)((int)rintf(a.x * f) & 15));
  d |= ((uint32_t)((int)rintf(a.y * f) & 15)) << 4;
  d |= ((uint32_t)((int)rintf(a.z * f) & 15)) << 8;
  d |= ((uint32_t)((int)rintf(a.w * f) & 15)) << 12;
  d |= ((uint32_t)((int)rintf(b.x * f) & 15)) << 16;
  d |= ((uint32_t)((int)rintf(b.y * f) & 15)) << 20;
  d |= ((uint32_t)((int)rintf(b.z * f) & 15)) << 24;
  d |= ((uint32_t)((int)rintf(b.w * f) & 15)) << 28;
  return d;
}
__device__ __forceinline__ int dot24_i4(const uint32_t qt[3], const uint32_t d[3]) {
  int acc = 0;
  asm("v_dot8_i32_i4 %0, %1, %2, %0" : "+v"(acc) : "v"(d[0]), "v"(qt[0]));
  asm("v_dot8_i32_i4 %0, %1, %2, %0" : "+v"(acc) : "v"(d[1]), "v"(qt[1]));
  asm("v_dot8_i32_i4 %0, %1, %2, %0" : "+v"(acc) : "v"(d[2]), "v"(qt[2]));
  return acc;
}

// ---------------- reciprocal L2 norms (fallback path only) ----------------
__global__ __launch_bounds__(256) void rnorm_kernel(const float* __restrict__ x,
                                                    float* __restrict__ rn,
                                                    int nrows) {
  int wave = threadIdx.x >> 6;
  int lane = threadIdx.x & 63;
  int row = blockIdx.x * 4 + wave;
  if (row >= nrows) return;
  const float4* p = (const float4*)(x + (size_t)row * D_DIM);
  float s = 0.f;
#pragma unroll
  for (int q = 0; q < 3; ++q) {
    float4 v = p[lane + 64 * q];
    s += v.x * v.x + v.y * v.y + v.z * v.z + v.w * v.w;
  }
#pragma unroll
  for (int o = 32; o; o >>= 1) s += __shfl_xor(s, o);
  if (lane == 0) rn[row] = 1.0f / fmaxf(sqrtf(s), 1e-8f);
}

// ---------------- labels -> padded i4 table: lane hl's 3 dwords + pad at 4*hl ----------------
__global__ __launch_bounds__(256) void prep_i4_kernel(const float* __restrict__ lbl,
                                                      uint32_t* __restrict__ tab,
                                                      float* __restrict__ tabscale,
                                                      int nrows) {
  int wave = threadIdx.x >> 6;
  int lane = threadIdx.x & 63;
  int row = blockIdx.x * 4 + wave;
  if (row >= nrows) return;
  // lane l owns elems [12l, 12l+12): float4s 3l..3l+2
  const float4* p = (const float4*)(lbl + (size_t)row * D_DIM);
  float4 v0 = p[3 * lane], v1 = p[3 * lane + 1], v2 = p[3 * lane + 2];
  float ss = v0.x * v0.x + v0.y * v0.y + v0.z * v0.z + v0.w * v0.w +
             v1.x * v1.x + v1.y * v1.y + v1.z * v1.z + v1.w * v1.w +
             v2.x * v2.x + v2.y * v2.y + v2.z * v2.z + v2.w * v2.w;
  float mx =
      fmaxf(fmaxf(fmaxf(fabsf(v0.x), fabsf(v0.y)), fmaxf(fabsf(v0.z), fabsf(v0.w))),
            fmaxf(fmaxf(fabsf(v1.x), fabsf(v1.y)), fmaxf(fabsf(v1.z), fabsf(v1.w))));
  mx = fmaxf(mx, fmaxf(fmaxf(fabsf(v2.x), fabsf(v2.y)), fmaxf(fabsf(v2.z), fabsf(v2.w))));
#pragma unroll
  for (int o = 32; o; o >>= 1) {
    ss += __shfl_xor(ss, o);
    mx = fmaxf(mx, __shfl_xor(mx, o));
  }
  float n = fmaxf(sqrtf(ss), 1e-8f);
  float max_u = mx / n;
  float S = (max_u > 0.f) ? 7.0f / max_u : 0.f;
  float f = S / n;
  // partner's v0 (lane pair 2k/2k+1 jointly covers contrast-lane k's 24 elems)
  float4 nb0;
  nb0.x = __shfl_xor(v0.x, 1);
  nb0.y = __shfl_xor(v0.y, 1);
  nb0.z = __shfl_xor(v0.z, 1);
  nb0.w = __shfl_xor(v0.w, 1);
  uint32_t* tp = tab + (size_t)row * RDP;
  int k = lane >> 1;
  if (!(lane & 1)) {
    // dwords 4k, 4k+1: elems 24k..24k+15
    uint2 st = make_uint2(pack8_i4(v0, v1, f), pack8_i4(v2, nb0, f));
    *(uint2*)(tp + 4 * k) = st;
  } else {
    // dwords 4k+2 (elems 24k+16..23), 4k+3 = pad
    uint2 st = make_uint2(pack8_i4(v1, v2, f), 0u);
    *(uint2*)(tp + 4 * k + 2) = st;
  }
  if (lane == 0) tabscale[row] = max_u / 7.0f;  // = 1/S (0 for zero rows)
}

// ---------------- contrastive loss: i4 gather, 1 dwordx4 per candidate ----------------
__global__ __launch_bounds__(256) void contrast_i4_kernel(
    const float* __restrict__ tgt, const uint32_t* __restrict__ tab,
    const float* __restrict__ tabscale, float* __restrict__ rowloss, int N) {
  int row = blockIdx.x;
  __shared__ int cand[104];
  __shared__ float sims[104];
  __shared__ float sscale[104];
  int tid = threadIdx.x;

  if (tid == 0) {
    cand[0] = row; sscale[0] = tabscale[row];
  } else if (tid <= KNEG) {
    int c = sample_negative(row, tid - 1, N);
    cand[tid] = c; sscale[tid] = tabscale[c];
  } else if (tid < 104) {
    cand[tid] = row; sscale[tid] = tabscale[row];  // pad: computed, never read
  }
  __syncthreads();

  int wave = tid >> 6, lane = tid & 63;
  int hl = lane & 31, hsel = lane >> 5;  // half-lane, half-select (A/B candidate)

  // target: half-lane hl owns elems [24*hl, 24*hl+24) = float4s 6*hl..6*hl+5
  const float4* tp = (const float4*)(tgt + (size_t)row * D_DIM);
  float4 e0 = tp[6 * hl], e1 = tp[6 * hl + 1], e2 = tp[6 * hl + 2],
         e3 = tp[6 * hl + 3], e4 = tp[6 * hl + 4], e5 = tp[6 * hl + 5];
  float ss = e0.x * e0.x + e0.y * e0.y + e0.z * e0.z + e0.w * e0.w +
             e1.x * e1.x + e1.y * e1.y + e1.z * e1.z + e1.w * e1.w +
             e2.x * e2.x + e2.y * e2.y + e2.z * e2.z + e2.w * e2.w +
             e3.x * e3.x + e3.y * e3.y + e3.z * e3.z + e3.w * e3.w +
             e4.x * e4.x + e4.y * e4.y + e4.z * e4.z + e4.w * e4.w +
             e5.x * e5.x + e5.y * e5.y + e5.z * e5.z + e5.w * e5.w;
  float mx = 0.f;
  mx = fmaxf(mx, fmaxf(fmaxf(fabsf(e0.x), fabsf(e0.y)), fmaxf(fabsf(e0.z), fabsf(e0.w))));
  mx = fmaxf(mx, fmaxf(fmaxf(fabsf(e1.x), fabsf(e1.y)), fmaxf(fabsf(e1.z), fabsf(e1.w))));
  mx = fmaxf(mx, fmaxf(fmaxf(fabsf(e2.x), fabsf(e2.y)), fmaxf(fabsf(e2.z), fabsf(e2.w))));
  mx = fmaxf(mx, fmaxf(fmaxf(fabsf(e3.x), fabsf(e3.y)), fmaxf(fabsf(e3.z), fabsf(e3.w))));
  mx = fmaxf(mx, fmaxf(fmaxf(fabsf(e4.x), fabsf(e4.y)), fmaxf(fabsf(e4.z), fabsf(e4.w))));
  mx = fmaxf(mx, fmaxf(fmaxf(fabsf(e5.x), fabsf(e5.y)), fmaxf(fabsf(e5.z), fabsf(e5.w))));
#pragma unroll
  for (int o = 16; o; o >>= 1) {  // within 32-lane half (each half has the full row)
    ss += __shfl_xor(ss, o);
    mx = fmaxf(mx, __shfl_xor(mx, o));
  }
  float n = fmaxf(sqrtf(ss), 1e-8f);
  float max_u = mx / n;
  float S = (max_u > 0.f) ? 7.0f / max_u : 0.f;
  float f = S / n;
  uint32_t qt[3];
  qt[0] = pack8_i4(e0, e1, f);
  qt[1] = pack8_i4(e2, e3, f);
  qt[2] = pack8_i4(e4, e5, f);
  float scT = (max_u / 7.0f) * INV_KAPPA;  // invSt * 1/kappa (uniform per row)

  // wave owns candidates [26w, 26w+26) = 13 pairs; batches of 4/4/4/1 pairs.
  int cb = wave * 26;
  uint32_t A[4][3], B[4][3];
  int s4[4];

#define LOAD_PAIR(dst, pidx)                                         \
  {                                                                  \
    int ci = cand[cb + 2 * (pidx) + hsel];                           \
    uint4 v = *((const uint4*)(tab + (size_t)ci * RDP) + hl);        \
    dst[0] = v.x; dst[1] = v.y; dst[2] = v.z;                        \
  }
#define LOAD_B4(dst, pb)                                             \
  LOAD_PAIR(dst[0], (pb) + 0) LOAD_PAIR(dst[1], (pb) + 1)            \
  LOAD_PAIR(dst[2], (pb) + 2) LOAD_PAIR(dst[3], (pb) + 3)
#define DOT_B4(src)                                                  \
  {                                                                  \
    s4[0] = dot24_i4(qt, src[0]); s4[1] = dot24_i4(qt, src[1]);      \
    s4[2] = dot24_i4(qt, src[2]); s4[3] = dot24_i4(qt, src[3]);      \
  }

  // multi-value butterfly within 32-lane half: 6 shuffles reduce 4 pairs;
  // lane hl<4 holds total of pair (hl) for its half.
#define RED_B4_STORE(pb)                                             \
  {                                                                  \
    int x01 = (hl & 1) ? s4[1] : s4[0];                              \
    int y01 = (hl & 1) ? s4[0] : s4[1];                              \
    x01 += __shfl_xor(y01, 1);                                       \
    int x23 = (hl & 1) ? s4[3] : s4[2];                              \
    int y23 = (hl & 1) ? s4[2] : s4[3];                              \
    x23 += __shfl_xor(y23, 1);                                       \
    int pr = (hl & 2) ? x23 : x01;                                   \
    int qr = (hl & 2) ? x01 : x23;                                   \
    pr += __shfl_xor(qr, 2);                                         \
    pr += __shfl_xor(pr, 4);                                         \
    pr += __shfl_xor(pr, 8);                                         \
    pr += __shfl_xor(pr, 16);                                        \
    if (hl < 4) {                                                    \
      int c = cb + 2 * ((pb) + hl) + hsel;                           \
      sims[c] = (float)pr * scT * sscale[c];                         \
    }                                                                \
  }

  LOAD_B4(A, 0)                       // pairs 0-3 in flight
  LOAD_B4(B, 4)                       // pairs 4-7 in flight
  DOT_B4(A) RED_B4_STORE(0)           // consume 0-3
  LOAD_B4(A, 8)                       // pairs 8-11 in flight
  DOT_B4(B) RED_B4_STORE(4)           // consume 4-7
  uint32_t T[3];
  LOAD_PAIR(T, 12)                    // tail pair in flight
  DOT_B4(A) RED_B4_STORE(8)           // consume 8-11
  {                                   // consume tail (pair 12: cands 24,25)
    int acc = dot24_i4(qt, T);
#pragma unroll
    for (int o = 16; o; o >>= 1) acc += __shfl_xor(acc, o);
    if (hl == 0) {
      int c = cb + 24 + hsel;
      sims[c] = (float)acc * scT * sscale[c];
    }
  }
#undef LOAD_PAIR
#undef LOAD_B4
#undef DOT_B4
#undef RED_B4_STORE
  __syncthreads();

  if (wave == 0) {
    float v0 = (lane < KNEG + 1) ? sims[lane] : -INFINITY;
    float v1 = (lane + 64 < KNEG + 1) ? sims[lane + 64] : -INFINITY;
    float m = fmaxf(v0, v1);
#pragma unroll
    for (int o = 32; o; o >>= 1) m = fmaxf(m, __shfl_xor(m, o));
    float e = ((lane < KNEG + 1) ? expf(v0 - m) : 0.f) +
              ((lane + 64 < KNEG + 1) ? expf(v1 - m) : 0.f);
#pragma unroll
    for (int o = 32; o; o >>= 1) e += __shfl_xor(e, o);
    if (lane == 0) rowloss[row] = m + logf(e) - sims[0];
  }
}

// ---------------- f32 fallback (tiny-ws safety; proven R0 path) ----------------
__global__ __launch_bounds__(256) void contrast_kernel(
    const float* __restrict__ tgt, const float* __restrict__ lbl,
    const float* __restrict__ rt, const float* __restrict__ rl,
    float* __restrict__ rowloss, int N) {
  int row = blockIdx.x;
  __shared__ int cand[104];
  __shared__ float sims[104];
  int tid = threadIdx.x;
  if (tid == 0) cand[0] = row;
  else if (tid <= KNEG) cand[tid] = sample_negative(row, tid - 1, N);
  __syncthreads();

  int wave = tid >> 6, lane = tid & 63;
  const float4* tp = (const float4*)(tgt + (size_t)row * D_DIM);
  float rscale = rt[row];
  float4 t0 = tp[lane], t1 = tp[lane + 64], t2 = tp[lane + 128];

  for (int c = wave; c < KNEG + 1; c += 4) {
    int ci = cand[c];
    const float4* lp = (const float4*)(lbl + (size_t)ci * D_DIM);
    float4 l0 = lp[lane], l1 = lp[lane + 64], l2 = lp[lane + 128];
    float s = t0.x * l0.x + t0.y * l0.y + t0.z * l0.z + t0.w * l0.w +
              t1.x * l1.x + t1.y * l1.y + t1.z * l1.z + t1.w * l1.w +
              t2.x * l2.x + t2.y * l2.y + t2.z * l2.z + t2.w * l2.w;
#pragma unroll
    for (int o = 32; o; o >>= 1) s += __shfl_xor(s, o);
    if (lane == 0) sims[c] = s * rscale * rl[ci] * INV_KAPPA;
  }
  __syncthreads();

  if (wave == 0) {
    float v0 = (lane < KNEG + 1) ? sims[lane] : -INFINITY;
    float v1 = (lane + 64 < KNEG + 1) ? sims[lane + 64] : -INFINITY;
    float m = fmaxf(v0, v1);
#pragma unroll
    for (int o = 32; o; o >>= 1) m = fmaxf(m, __shfl_xor(m, o));
    float e = ((lane < KNEG + 1) ? expf(v0 - m) : 0.f) +
              ((lane + 64 < KNEG + 1) ? expf(v1 - m) : 0.f);
#pragma unroll
    for (int o = 32; o; o >>= 1) e += __shfl_xor(e, o);
    if (lane == 0) rowloss[row] = m + logf(e) - sims[0];
  }
}

// ---------------- final deterministic reduction ----------------
__global__ __launch_bounds__(256) void finalize_kernel(
    const float* __restrict__ rowloss, const float* __restrict__ perp,
    float* __restrict__ out, int N, int GV) {
  int tid = threadIdx.x;
  float s = 0.f;
  for (int i = tid; i < N; i += 256) s += rowloss[i];
  float dv = 0.f;
  for (int i = tid; i < GV; i += 256) {
    float p = perp[i];
    dv += p * logf(p + 1e-9f);
  }
#pragma unroll
  for (int o = 32; o; o >>= 1) {
    s += __shfl_xor(s, o);
    dv += __shfl_xor(dv, o);
  }
  __shared__ float ss[4], sd[4];
  if ((tid & 63) == 0) { ss[tid >> 6] = s; sd[tid >> 6] = dv; }
  __syncthreads();
  if (tid == 0) {
    float S = ss[0] + ss[1] + ss[2] + ss[3];
    float DV = sd[0] + sd[1] + sd[2] + sd[3];
    out[0] = S / (float)N + 0.1f * (-DV / (float)GV);
  }
}

extern "C" void kernel_launch(void* const* d_in, const int* in_sizes, int n_in,
                              void* d_out, int out_size, void* d_ws, size_t ws_size,
                              hipStream_t stream) {
  const float* enc = (const float*)d_in[0];   // encoder_out (targets)
  const float* qf  = (const float*)d_in[1];   // quantized_features (labels)
  const float* perp = (const float*)d_in[2];  // perplexity
  int N = in_sizes[0] / D_DIM;   // 4096
  int GV = in_sizes[2];          // 640

  float* ws = (float*)d_ws;
  float* rowloss = ws;                        // N floats
  float* tabscale = ws + N;                   // N floats
  uint32_t* tab = (uint32_t*)(ws + 2 * N);    // N*128 dwords (padded i4 table)

  size_t needed = (size_t)2 * N * 4 + (size_t)N * RDP * 4;
  if (ws_size >= needed) {
    prep_i4_kernel<<<(N + 3) / 4, 256, 0, stream>>>(qf, tab, tabscale, N);
    contrast_i4_kernel<<<N, 256, 0, stream>>>(enc, tab, tabscale, rowloss, N);
  } else {
    float* rt = ws + N;
    float* rl = ws + 2 * N;
    rnorm_kernel<<<(N + 3) / 4, 256, 0, stream>>>(enc, rt, N);
    rnorm_kernel<<<(N + 3) / 4, 256, 0, stream>>>(qf, rl, N);
    contrast_kernel<<<N, 256, 0, stream>>>(enc, qf, rt, rl, rowloss, N);
  }
  finalize_kernel<<<1, 256, 0, stream>>>(rowloss, perp, (float*)d_out, N, GV);
}

// Round 12
// 33.437 us; speedup vs baseline: 1.0452x; 1.0452x over previous
//
#include <hip/hip_runtime.h>
#include <stdint.h>

#define D_DIM 768
#define KNEG 100
#define INV_KAPPA 10.0f
#define RD4 96            // dwords per i4 row (768 * 4bit / 32)

// ---------------- threefry2x32 (exact JAX semantics) ----------------
__device__ __forceinline__ uint32_t rotl32(uint32_t x, int r) {
  return (x << r) | (x >> (32 - r));
}

#define TF_R4(a, b, c, d)                        \
  x0 += x1; x1 = rotl32(x1, a); x1 ^= x0;        \
  x0 += x1; x1 = rotl32(x1, b); x1 ^= x0;        \
  x0 += x1; x1 = rotl32(x1, c); x1 ^= x0;        \
  x0 += x1; x1 = rotl32(x1, d); x1 ^= x0;

__device__ __forceinline__ void threefry2x32(uint32_t ks0, uint32_t ks1,
                                             uint32_t x0, uint32_t x1,
                                             uint32_t& o0, uint32_t& o1) {
  uint32_t ks2 = ks0 ^ ks1 ^ 0x1BD11BDAu;
  x0 += ks0; x1 += ks1;
  TF_R4(13, 15, 26, 6)   x0 += ks1; x1 += ks2 + 1u;
  TF_R4(17, 29, 16, 24)  x0 += ks2; x1 += ks0 + 2u;
  TF_R4(13, 15, 26, 6)   x0 += ks0; x1 += ks1 + 3u;
  TF_R4(17, 29, 16, 24)  x0 += ks1; x1 += ks2 + 4u;
  TF_R4(13, 15, 26, 6)   x0 += ks2; x1 += ks0 + 5u;
  o0 = x0; o1 = x1;
}

__device__ __forceinline__ int sample_negative(int row, int k, int N) {
  // replicate jax.random.randint(key(42), (N,100), 0, N-1) element (row,k)
  uint32_t a0, b0, a1, b1;
  threefry2x32(0u, 42u, 0u, 2u, a0, b0);   // constant-folds at -O3
  threefry2x32(0u, 42u, 1u, 3u, a1, b1);
  uint32_t total = (uint32_t)N * KNEG;
  uint32_t half = total >> 1;
  uint32_t j = (uint32_t)row * KNEG + (uint32_t)k;
  uint32_t x0 = (j < half) ? j : (j - half);
  uint32_t x1 = (j < half) ? (j + half) : j;
  uint32_t h0, h1, l0, l1;
  threefry2x32(a0, a1, x0, x1, h0, h1);
  threefry2x32(b0, b1, x0, x1, l0, l1);
  uint32_t hb = (j < half) ? h0 : h1;
  uint32_t lb = (j < half) ? l0 : l1;
  uint32_t span = (uint32_t)(N - 1);
  uint32_t mult = 65536u % span;
  mult = (mult * mult) % span;
  uint32_t off = ((hb % span) * mult + (lb % span)) % span;
  int idx = (int)off;
  if (idx >= row) idx++;  // skip self
  return idx;
}

// ---------------- i4 pack + hw dot8 (inline asm: assembles or build fails) ----------------
__device__ __forceinline__ uint32_t pack8_i4(float4 a, float4 b, float f) {
  uint32_t d = 0;
  d |= ((uint32_t)((int)rintf(a.x * f) & 15));
  d |= ((uint32_t)((int)rintf(a.y * f) & 15)) << 4;
  d |= ((uint32_t)((int)rintf(a.z * f) & 15)) << 8;
  d |= ((uint32_t)((int)rintf(a.w * f) & 15)) << 12;
  d |= ((uint32_t)((int)rintf(b.x * f) & 15)) << 16;
  d |= ((uint32_t)((int)rintf(b.y * f) & 15)) << 20;
  d |= ((uint32_t)((int)rintf(b.z * f) & 15)) << 24;
  d |= ((uint32_t)((int)rintf(b.w * f) & 15)) << 28;
  return d;
}
__device__ __forceinline__ int dot24_i4(const uint32_t qt[3], const uint32_t d[3]) {
  int acc = 0;
  asm("v_dot8_i32_i4 %0, %1, %2, %0" : "+v"(acc) : "v"(d[0]), "v"(qt[0]));
  asm("v_dot8_i32_i4 %0, %1, %2, %0" : "+v"(acc) : "v"(d[1]), "v"(qt[1]));
  asm("v_dot8_i32_i4 %0, %1, %2, %0" : "+v"(acc) : "v"(d[2]), "v"(qt[2]));
  return acc;
}

// ---------------- reciprocal L2 norms (fallback path only) ----------------
__global__ __launch_bounds__(256) void rnorm_kernel(const float* __restrict__ x,
                                                    float* __restrict__ rn,
                                                    int nrows) {
  int wave = threadIdx.x >> 6;
  int lane = threadIdx.x & 63;
  int row = blockIdx.x * 4 + wave;
  if (row >= nrows) return;
  const float4* p = (const float4*)(x + (size_t)row * D_DIM);
  float s = 0.f;
#pragma unroll
  for (int q = 0; q < 3; ++q) {
    float4 v = p[lane + 64 * q];
    s += v.x * v.x + v.y * v.y + v.z * v.z + v.w * v.w;
  }
#pragma unroll
  for (int o = 32; o; o >>= 1) s += __shfl_xor(s, o);
  if (lane == 0) rn[row] = 1.0f / fmaxf(sqrtf(s), 1e-8f);
}

// ---------------- normalize labels -> i4 table (per-row scale), row = 96 dwords ----------------
__global__ __launch_bounds__(256) void prep_i4_kernel(const float* __restrict__ lbl,
                                                      uint32_t* __restrict__ tab,
                                                      float* __restrict__ tabscale,
                                                      int nrows) {
  int wave = threadIdx.x >> 6;
  int lane = threadIdx.x & 63;
  int row = blockIdx.x * 4 + wave;
  if (row >= nrows) return;
  const float4* p = (const float4*)(lbl + (size_t)row * D_DIM);
  float4 v0 = make_float4(0, 0, 0, 0), v1 = v0, v2 = v0, v3 = v0;
  float ss = 0.f, mx = 0.f;
  if (lane < 48) {  // lane owns elems [16*lane, 16*lane+16)
    v0 = p[4 * lane]; v1 = p[4 * lane + 1]; v2 = p[4 * lane + 2]; v3 = p[4 * lane + 3];
    ss = v0.x * v0.x + v0.y * v0.y + v0.z * v0.z + v0.w * v0.w +
         v1.x * v1.x + v1.y * v1.y + v1.z * v1.z + v1.w * v1.w +
         v2.x * v2.x + v2.y * v2.y + v2.z * v2.z + v2.w * v2.w +
         v3.x * v3.x + v3.y * v3.y + v3.z * v3.z + v3.w * v3.w;
    mx = fmaxf(fmaxf(fmaxf(fabsf(v0.x), fabsf(v0.y)), fmaxf(fabsf(v0.z), fabsf(v0.w))),
               fmaxf(fmaxf(fabsf(v1.x), fabsf(v1.y)), fmaxf(fabsf(v1.z), fabsf(v1.w))));
    mx = fmaxf(mx,
               fmaxf(fmaxf(fmaxf(fabsf(v2.x), fabsf(v2.y)), fmaxf(fabsf(v2.z), fabsf(v2.w))),
                     fmaxf(fmaxf(fabsf(v3.x), fabsf(v3.y)), fmaxf(fabsf(v3.z), fabsf(v3.w)))));
  }
#pragma unroll
  for (int o = 32; o; o >>= 1) {
    ss += __shfl_xor(ss, o);
    mx = fmaxf(mx, __shfl_xor(mx, o));
  }
  float n = fmaxf(sqrtf(ss), 1e-8f);
  float max_u = mx / n;
  float S = (max_u > 0.f) ? 7.0f / max_u : 0.f;
  float f = S / n;
  if (lane < 48) {
    uint32_t d0 = pack8_i4(v0, v1, f);
    uint32_t d1 = pack8_i4(v2, v3, f);
    ((uint2*)(tab + (size_t)row * RD4))[lane] = make_uint2(d0, d1);
  }
  if (lane == 0) tabscale[row] = max_u / 7.0f;  // = 1/S (0 for zero rows)
}

// ---------------- contrastive loss: i4 gather, pair-of-candidates per wave ----------------
__global__ __launch_bounds__(256) void contrast_i4_kernel(
    const float* __restrict__ tgt, const uint32_t* __restrict__ tab,
    const float* __restrict__ tabscale, float* __restrict__ rowloss, int N) {
  int row = blockIdx.x;
  __shared__ int cand[104];
  __shared__ float sims[104];
  __shared__ float sscale[104];
  int tid = threadIdx.x;

  if (tid == 0) {
    cand[0] = row; sscale[0] = tabscale[row];
  } else if (tid <= KNEG) {
    int c = sample_negative(row, tid - 1, N);
    cand[tid] = c; sscale[tid] = tabscale[c];
  } else if (tid < 104) {
    cand[tid] = row; sscale[tid] = tabscale[row];  // pad: computed, never read
  }
  __syncthreads();

  int wave = tid >> 6, lane = tid & 63;
  int hl = lane & 31, hsel = lane >> 5;  // half-lane, half-select (A/B candidate)

  // target fragment: dwords d = hl + 32*i (i=0..2); each half-wave holds the full row
  const float4* tp = (const float4*)(tgt + (size_t)row * D_DIM);
  float4 e0, e1, e2, e3, e4, e5;
  {
    int d0 = hl, d1 = hl + 32, d2 = hl + 64;
    e0 = tp[2 * d0]; e1 = tp[2 * d0 + 1];
    e2 = tp[2 * d1]; e3 = tp[2 * d1 + 1];
    e4 = tp[2 * d2]; e5 = tp[2 * d2 + 1];
  }
  float ss = e0.x * e0.x + e0.y * e0.y + e0.z * e0.z + e0.w * e0.w +
             e1.x * e1.x + e1.y * e1.y + e1.z * e1.z + e1.w * e1.w +
             e2.x * e2.x + e2.y * e2.y + e2.z * e2.z + e2.w * e2.w +
             e3.x * e3.x + e3.y * e3.y + e3.z * e3.z + e3.w * e3.w +
             e4.x * e4.x + e4.y * e4.y + e4.z * e4.z + e4.w * e4.w +
             e5.x * e5.x + e5.y * e5.y + e5.z * e5.z + e5.w * e5.w;
  float mx = 0.f;
  mx = fmaxf(mx, fmaxf(fmaxf(fabsf(e0.x), fabsf(e0.y)), fmaxf(fabsf(e0.z), fabsf(e0.w))));
  mx = fmaxf(mx, fmaxf(fmaxf(fabsf(e1.x), fabsf(e1.y)), fmaxf(fabsf(e1.z), fabsf(e1.w))));
  mx = fmaxf(mx, fmaxf(fmaxf(fabsf(e2.x), fabsf(e2.y)), fmaxf(fabsf(e2.z), fabsf(e2.w))));
  mx = fmaxf(mx, fmaxf(fmaxf(fabsf(e3.x), fabsf(e3.y)), fmaxf(fabsf(e3.z), fabsf(e3.w))));
  mx = fmaxf(mx, fmaxf(fmaxf(fabsf(e4.x), fabsf(e4.y)), fmaxf(fabsf(e4.z), fabsf(e4.w))));
  mx = fmaxf(mx, fmaxf(fmaxf(fabsf(e5.x), fabsf(e5.y)), fmaxf(fabsf(e5.z), fabsf(e5.w))));
#pragma unroll
  for (int o = 16; o; o >>= 1) {  // within 32-lane half (each half has the full row)
    ss += __shfl_xor(ss, o);
    mx = fmaxf(mx, __shfl_xor(mx, o));
  }
  float n = fmaxf(sqrtf(ss), 1e-8f);
  float max_u = mx / n;
  float S = (max_u > 0.f) ? 7.0f / max_u : 0.f;
  float f = S / n;
  uint32_t qt[3];
  qt[0] = pack8_i4(e0, e1, f);
  qt[1] = pack8_i4(e2, e3, f);
  qt[2] = pack8_i4(e4, e5, f);
  float scT = (max_u / 7.0f) * INV_KAPPA;  // invSt * 1/kappa (uniform per row)

  // wave owns candidates [26w, 26w+26) = 13 pairs; batches of 4/4/4/1 pairs.
  int cb = wave * 26;
  uint32_t A[4][3], B[4][3];
  int s4[4];

#define LOAD_PAIR(dst, pidx)                                         \
  {                                                                  \
    int ci = cand[cb + 2 * (pidx) + hsel];                           \
    const uint32_t* pp = tab + (size_t)ci * RD4;                     \
    dst[0] = pp[hl]; dst[1] = pp[hl + 32]; dst[2] = pp[hl + 64];     \
  }
#define LOAD_B4(dst, pb)                                             \
  LOAD_PAIR(dst[0], (pb) + 0) LOAD_PAIR(dst[1], (pb) + 1)            \
  LOAD_PAIR(dst[2], (pb) + 2) LOAD_PAIR(dst[3], (pb) + 3)
#define DOT_B4(src)                                                  \
  {                                                                  \
    s4[0] = dot24_i4(qt, src[0]); s4[1] = dot24_i4(qt, src[1]);      \
    s4[2] = dot24_i4(qt, src[2]); s4[3] = dot24_i4(qt, src[3]);      \
  }

  // multi-value butterfly within 32-lane half: 6 shuffles reduce 4 pairs;
  // lane hl<4 holds total of pair (hl) for its half.
#define RED_B4_STORE(pb)                                             \
  {                                                                  \
    int x01 = (hl & 1) ? s4[1] : s4[0];                              \
    int y01 = (hl & 1) ? s4[0] : s4[1];                              \
    x01 += __shfl_xor(y01, 1);                                       \
    int x23 = (hl & 1) ? s4[3] : s4[2];                              \
    int y23 = (hl & 1) ? s4[2] : s4[3];                              \
    x23 += __shfl_xor(y23, 1);                                       \
    int pr = (hl & 2) ? x23 : x01;                                   \
    int qr = (hl & 2) ? x01 : x23;                                   \
    pr += __shfl_xor(qr, 2);                                         \
    pr += __shfl_xor(pr, 4);                                         \
    pr += __shfl_xor(pr, 8);                                         \
    pr += __shfl_xor(pr, 16);                                        \
    if (hl < 4) {                                                    \
      int c = cb + 2 * ((pb) + hl) + hsel;                           \
      sims[c] = (float)pr * scT * sscale[c];                         \
    }                                                                \
  }

  LOAD_B4(A, 0)                       // pairs 0-3 in flight
  LOAD_B4(B, 4)                       // pairs 4-7 in flight
  DOT_B4(A) RED_B4_STORE(0)           // consume 0-3
  LOAD_B4(A, 8)                       // pairs 8-11 in flight
  DOT_B4(B) RED_B4_STORE(4)           // consume 4-7
  uint32_t T[3];
  LOAD_PAIR(T, 12)                    // tail pair in flight
  DOT_B4(A) RED_B4_STORE(8)           // consume 8-11
  {                                   // consume tail (pair 12: cands 24,25)
    int acc = dot24_i4(qt, T);
#pragma unroll
    for (int o = 16; o; o >>= 1) acc += __shfl_xor(acc, o);
    if (hl == 0) {
      int c = cb + 24 + hsel;
      sims[c] = (float)acc * scT * sscale[c];
    }
  }
#undef LOAD_PAIR
#undef LOAD_B4
#undef DOT_B4
#undef RED_B4_STORE
  __syncthreads();

  if (wave == 0) {
    float v0 = (lane < KNEG + 1) ? sims[lane] : -INFINITY;
    float v1 = (lane + 64 < KNEG + 1) ? sims[lane + 64] : -INFINITY;
    float m = fmaxf(v0, v1);
#pragma unroll
    for (int o = 32; o; o >>= 1) m = fmaxf(m, __shfl_xor(m, o));
    float e = ((lane < KNEG + 1) ? expf(v0 - m) : 0.f) +
              ((lane + 64 < KNEG + 1) ? expf(v1 - m) : 0.f);
#pragma unroll
    for (int o = 32; o; o >>= 1) e += __shfl_xor(e, o);
    if (lane == 0) rowloss[row] = m + logf(e) - sims[0];
  }
}

// ---------------- f32 fallback (tiny-ws safety; proven R0 path) ----------------
__global__ __launch_bounds__(256) void contrast_kernel(
    const float* __restrict__ tgt, const float* __restrict__ lbl,
    const float* __restrict__ rt, const float* __restrict__ rl,
    float* __restrict__ rowloss, int N) {
  int row = blockIdx.x;
  __shared__ int cand[104];
  __shared__ float sims[104];
  int tid = threadIdx.x;
  if (tid == 0) cand[0] = row;
  else if (tid <= KNEG) cand[tid] = sample_negative(row, tid - 1, N);
  __syncthreads();

  int wave = tid >> 6, lane = tid & 63;
  const float4* tp = (const float4*)(tgt + (size_t)row * D_DIM);
  float rscale = rt[row];
  float4 t0 = tp[lane], t1 = tp[lane + 64], t2 = tp[lane + 128];

  for (int c = wave; c < KNEG + 1; c += 4) {
    int ci = cand[c];
    const float4* lp = (const float4*)(lbl + (size_t)ci * D_DIM);
    float4 l0 = lp[lane], l1 = lp[lane + 64], l2 = lp[lane + 128];
    float s = t0.x * l0.x + t0.y * l0.y + t0.z * l0.z + t0.w * l0.w +
              t1.x * l1.x + t1.y * l1.y + t1.z * l1.z + t1.w * l1.w +
              t2.x * l2.x + t2.y * l2.y + t2.z * l2.z + t2.w * l2.w;
#pragma unroll
    for (int o = 32; o; o >>= 1) s += __shfl_xor(s, o);
    if (lane == 0) sims[c] = s * rscale * rl[ci] * INV_KAPPA;
  }
  __syncthreads();

  if (wave == 0) {
    float v0 = (lane < KNEG + 1) ? sims[lane] : -INFINITY;
    float v1 = (lane + 64 < KNEG + 1) ? sims[lane + 64] : -INFINITY;
    float m = fmaxf(v0, v1);
#pragma unroll
    for (int o = 32; o; o >>= 1) m = fmaxf(m, __shfl_xor(m, o));
    float e = ((lane < KNEG + 1) ? expf(v0 - m) : 0.f) +
              ((lane + 64 < KNEG + 1) ? expf(v1 - m) : 0.f);
#pragma unroll
    for (int o = 32; o; o >>= 1) e += __shfl_xor(e, o);
    if (lane == 0) rowloss[row] = m + logf(e) - sims[0];
  }
}

// ---------------- final deterministic reduction ----------------
__global__ __launch_bounds__(256) void finalize_kernel(
    const float* __restrict__ rowloss, const float* __restrict__ perp,
    float* __restrict__ out, int N, int GV) {
  int tid = threadIdx.x;
  float s = 0.f;
  for (int i = tid; i < N; i += 256) s += rowloss[i];
  float dv = 0.f;
  for (int i = tid; i < GV; i += 256) {
    float p = perp[i];
    dv += p * logf(p + 1e-9f);
  }
#pragma unroll
  for (int o = 32; o; o >>= 1) {
    s += __shfl_xor(s, o);
    dv += __shfl_xor(dv, o);
  }
  __shared__ float ss[4], sd[4];
  if ((tid & 63) == 0) { ss[tid >> 6] = s; sd[tid >> 6] = dv; }
  __syncthreads();
  if (tid == 0) {
    float S = ss[0] + ss[1] + ss[2] + ss[3];
    float DV = sd[0] + sd[1] + sd[2] + sd[3];
    out[0] = S / (float)N + 0.1f * (-DV / (float)GV);
  }
}

extern "C" void kernel_launch(void* const* d_in, const int* in_sizes, int n_in,
                              void* d_out, int out_size, void* d_ws, size_t ws_size,
                              hipStream_t stream) {
  const float* enc = (const float*)d_in[0];   // encoder_out (targets)
  const float* qf  = (const float*)d_in[1];   // quantized_features (labels)
  const float* perp = (const float*)d_in[2];  // perplexity
  int N = in_sizes[0] / D_DIM;   // 4096
  int GV = in_sizes[2];          // 640

  float* ws = (float*)d_ws;
  float* rowloss = ws;                        // N floats
  float* tabscale = ws + N;                   // N floats
  uint32_t* tab = (uint32_t*)(ws + 2 * N);    // N*96 dwords (i4 table)

  size_t needed = (size_t)2 * N * 4 + (size_t)N * RD4 * 4;
  if (ws_size >= needed) {
    prep_i4_kernel<<<(N + 3) / 4, 256, 0, stream>>>(qf, tab, tabscale, N);
    contrast_i4_kernel<<<N, 256, 0, stream>>>(enc, tab, tabscale, rowloss, N);
  } else {
    float* rt = ws + N;
    float* rl = ws + 2 * N;
    rnorm_kernel<<<(N + 3) / 4, 256, 0, stream>>>(enc, rt, N);
    rnorm_kernel<<<(N + 3) / 4, 256, 0, stream>>>(qf, rl, N);
    contrast_kernel<<<N, 256, 0, stream>>>(enc, qf, rt, rl, rowloss, N);
  }
  finalize_kernel<<<1, 256, 0, stream>>>(rowloss, perp, (float*)d_out, N, GV);
}